// Round 1
// baseline (109.543 us; speedup 1.0000x reference)
//
#include <hip/hip_runtime.h>

#define B 2
#define N 4096
#define C 192
#define H 8
#define D 24
#define CH 32           // chunks per batch for partial xw
#define CHN (N / CH)    // 128 rows per chunk

// ws layout (floats):
//   e    : [B][N][H]      = 65536
//   part : [B][CH][H][C]  = 98304
//   y    : [B][C]         = 384
#define E_OFF    0
#define PART_OFF 65536
#define Y_OFF    (65536 + 98304)

// K1: e[b,n,h] = exp( (x[b,n,:] . Wk_sum[h,:]) * scale )
// Wk_sum[h,c] = sum_d W_qkv[(C + h*D + d), c]  (computed per-block in LDS)
__global__ __launch_bounds__(256) void k1_exp(const float* __restrict__ x,
                                              const float* __restrict__ Wqkv,
                                              const float* __restrict__ scale,
                                              float* __restrict__ e) {
    __shared__ __align__(16) float wk[H * C];   // 1536 floats
    const int tid = threadIdx.x;
    for (int i = tid; i < H * C; i += 256) {
        int h = i / C, c = i % C;
        float s = 0.f;
        const float* wr = Wqkv + (size_t)(C + h * D) * C + c;
        #pragma unroll
        for (int d = 0; d < D; ++d) s += wr[(size_t)d * C];
        wk[i] = s;
    }
    __syncthreads();

    const int r = blockIdx.x * 256 + tid;        // row in [0, B*N)
    const float* xr = x + (size_t)r * C;
    float acc[H] = {};
    for (int c = 0; c < C; c += 4) {
        float4 xv = *(const float4*)(xr + c);
        #pragma unroll
        for (int h = 0; h < H; ++h) {
            float4 wv = *(const float4*)(wk + h * C + c);  // wave-uniform -> LDS broadcast
            acc[h] += xv.x * wv.x + xv.y * wv.y + xv.z * wv.z + xv.w * wv.w;
        }
    }
    const float s = scale[0];
    float4 e0, e1;
    e0.x = __expf(acc[0] * s); e0.y = __expf(acc[1] * s);
    e0.z = __expf(acc[2] * s); e0.w = __expf(acc[3] * s);
    e1.x = __expf(acc[4] * s); e1.y = __expf(acc[5] * s);
    e1.z = __expf(acc[6] * s); e1.w = __expf(acc[7] * s);
    float* er = e + (size_t)r * H;
    *(float4*)er       = e0;
    *(float4*)(er + 4) = e1;
}

// K2: part[b,ch,h,c] = sum_{n in chunk} e[b,n,h] * x[b,n,c]
__global__ __launch_bounds__(192) void k2_partial(const float* __restrict__ x,
                                                  const float* __restrict__ e,
                                                  float* __restrict__ part) {
    const int b  = blockIdx.x / CH;
    const int ch = blockIdx.x % CH;
    const int c  = threadIdx.x;                  // 0..191
    const int n0 = ch * CHN;
    const float* xb = x + (size_t)(b * N + n0) * C + c;
    const float* eb = e + (size_t)(b * N + n0) * H;
    float acc[H] = {};
    for (int n = 0; n < CHN; ++n) {
        float  xv  = xb[(size_t)n * C];                      // coalesced across lanes
        float4 ea  = *(const float4*)(eb + n * H);           // wave-uniform -> s_load
        float4 eb4 = *(const float4*)(eb + n * H + 4);
        acc[0] += ea.x  * xv; acc[1] += ea.y  * xv;
        acc[2] += ea.z  * xv; acc[3] += ea.w  * xv;
        acc[4] += eb4.x * xv; acc[5] += eb4.y * xv;
        acc[6] += eb4.z * xv; acc[7] += eb4.w * xv;
    }
    float* pr = part + (size_t)(b * CH + ch) * (H * C) + c;
    #pragma unroll
    for (int h = 0; h < H; ++h) pr[h * C] = acc[h];
}

// K3: reduce partials -> xw; Z = sum e; obar[h,d] = (xw[h,:].Wv[h*D+d,:]) / Z[h];
//     y[o] = obar . Wproj[o,:] + bproj[o]
__global__ __launch_bounds__(256) void k3_final(const float* __restrict__ Wqkv,
                                                const float* __restrict__ Wproj,
                                                const float* __restrict__ bproj,
                                                const float* __restrict__ e,
                                                const float* __restrict__ part,
                                                float* __restrict__ y) {
    const int b = blockIdx.x, tid = threadIdx.x;
    __shared__ float red[H * 256];
    __shared__ float zf[H];
    __shared__ float xwl[H * C];
    __shared__ float obar[C];

    // Z[h] = sum_n e[b,n,h]
    float z[H] = {};
    const float* ebase = e + (size_t)b * N * H;
    for (int n = tid; n < N; n += 256) {
        const float* er = ebase + (size_t)n * H;   // 8 contiguous floats per thread
        #pragma unroll
        for (int h = 0; h < H; ++h) z[h] += er[h];
    }
    #pragma unroll
    for (int h = 0; h < H; ++h) red[h * 256 + tid] = z[h];
    __syncthreads();
    for (int s = 128; s > 0; s >>= 1) {
        if (tid < s) {
            #pragma unroll
            for (int h = 0; h < H; ++h) red[h * 256 + tid] += red[h * 256 + tid + s];
        }
        __syncthreads();
    }
    if (tid < H) zf[tid] = red[tid * 256];

    // xw[h,c] = sum_ch part
    const float* pb = part + (size_t)b * CH * H * C;
    for (int i = tid; i < H * C; i += 256) {
        float s = 0.f;
        for (int ch = 0; ch < CH; ++ch) s += pb[(size_t)ch * H * C + i];
        xwl[i] = s;
    }
    __syncthreads();

    // obar[t] for t = h*D + d  (Wv row = 2C + t)
    if (tid < C) {
        const int h = tid / D;
        const float* wv  = Wqkv + (size_t)(2 * C + tid) * C;
        const float* xwh = xwl + h * C;
        float s = 0.f;
        for (int cc = 0; cc < C; ++cc) s += xwh[cc] * wv[cc];
        obar[tid] = s / zf[h];
    }
    __syncthreads();

    // y[o] = obar . Wproj[o,:] + bproj[o]
    if (tid < C) {
        const float* wp = Wproj + (size_t)tid * C;
        float s = bproj[tid];
        for (int cc = 0; cc < C; ++cc) s += obar[cc] * wp[cc];
        y[(size_t)b * C + tid] = s;
    }
}

// K4: out[b,n,:] = y[b,:] broadcast, float4 stores
__global__ __launch_bounds__(256) void k4_bcast(const float* __restrict__ y,
                                                float* __restrict__ out) {
    const int total4 = B * N * C / 4;            // 393216
    const int perB4  = N * C / 4;                // 196608
    int i = blockIdx.x * 256 + threadIdx.x;
    for (; i < total4; i += gridDim.x * 256) {
        int b  = i / perB4;
        int o4 = i % (C / 4);
        float4 v = *(const float4*)(y + (size_t)b * C + o4 * 4);
        ((float4*)out)[i] = v;
    }
}

extern "C" void kernel_launch(void* const* d_in, const int* in_sizes, int n_in,
                              void* d_out, int out_size, void* d_ws, size_t ws_size,
                              hipStream_t stream) {
    const float* x     = (const float*)d_in[0];
    const float* Wqkv  = (const float*)d_in[1];
    const float* Wproj = (const float*)d_in[2];
    const float* bproj = (const float*)d_in[3];
    const float* scale = (const float*)d_in[4];
    float* out = (float*)d_out;
    float* ws  = (float*)d_ws;
    float* e    = ws + E_OFF;
    float* part = ws + PART_OFF;
    float* y    = ws + Y_OFF;

    k1_exp<<<(B * N) / 256, 256, 0, stream>>>(x, Wqkv, scale, e);
    k2_partial<<<B * CH, 192, 0, stream>>>(x, e, part);
    k3_final<<<B, 256, 0, stream>>>(Wqkv, Wproj, bproj, e, part, y);
    k4_bcast<<<256, 256, 0, stream>>>(y, out);
}

// Round 2
// 97.244 us; speedup vs baseline: 1.1265x; 1.1265x over previous
//
#include <hip/hip_runtime.h>

#define B 2
#define N 4096
#define C 192
#define H 8
#define D 24
#define NCH 128          // chunks per batch
#define CHN 32           // rows per chunk (N/NCH)

// ws layout (float offsets)
#define WK_OFF    0        // wk   [H][C]        = 1536
#define E_OFF     2048     // e    [B][N][H]     = 65536
#define PART_OFF  67584    // part [B][NCH][H][C]= 393216
#define XW_OFF    460800   // xw   [B][H][C]     = 3072
#define ZP_OFF    463872   // zp   [B][8][H]     = 128
#define OBAR_OFF  464000   // obar [B][C]        = 384
#define Y_OFF     464384   // y    [B][C]        = 384

// wk[h][c] = sum_d Wqkv[(C + h*D + d)*C + c]
__global__ __launch_bounds__(192) void k_wk(const float* __restrict__ Wqkv,
                                            float* __restrict__ wk) {
    const int h = blockIdx.x;          // 0..7
    const int c = threadIdx.x;         // 0..191
    const float* wr = Wqkv + (size_t)(C + h * D) * C + c;
    float s = 0.f;
    #pragma unroll
    for (int d = 0; d < D; ++d) s += wr[(size_t)d * C];
    wk[h * C + c] = s;
}

// e[r][h] = exp( (x[r,:] . wk[h,:]) * scale ) — thread-per-row, wk via uniform (scalar) loads
__global__ __launch_bounds__(64) void k_e(const float* __restrict__ x,
                                          const float* __restrict__ wk,
                                          const float* __restrict__ scale,
                                          float* __restrict__ e) {
    const int r = blockIdx.x * 64 + threadIdx.x;   // 0..8191
    const float* xr = x + (size_t)r * C;
    const float4* wk4 = (const float4*)wk;         // [h*48 + c4], wave-uniform
    float acc[H] = {};
    for (int c4 = 0; c4 < C / 4; ++c4) {
        float4 xv = ((const float4*)xr)[c4];
        #pragma unroll
        for (int h = 0; h < H; ++h) {
            float4 wv = wk4[h * (C / 4) + c4];
            acc[h] += xv.x * wv.x + xv.y * wv.y + xv.z * wv.z + xv.w * wv.w;
        }
    }
    const float s = scale[0];
    float4 e0, e1;
    e0.x = __expf(acc[0] * s); e0.y = __expf(acc[1] * s);
    e0.z = __expf(acc[2] * s); e0.w = __expf(acc[3] * s);
    e1.x = __expf(acc[4] * s); e1.y = __expf(acc[5] * s);
    e1.z = __expf(acc[6] * s); e1.w = __expf(acc[7] * s);
    float4* er = (float4*)(e + (size_t)r * H);
    er[0] = e0; er[1] = e1;
}

// part[b][ch][h][c] = sum_{n in 32-row chunk} e[row][h] * x[row][c]
__global__ __launch_bounds__(192) void k_part(const float* __restrict__ x,
                                              const float* __restrict__ e,
                                              float* __restrict__ part) {
    const int b  = blockIdx.x / NCH;
    const int ch = blockIdx.x % NCH;
    const int c  = threadIdx.x;                    // 0..191
    const int row0 = b * N + ch * CHN;
    const float* xb = x + (size_t)row0 * C + c;
    float acc[H] = {};
    for (int n = 0; n < CHN; ++n) {
        float xv = xb[(size_t)n * C];                              // coalesced
        const float4* er = (const float4*)(e + (size_t)(row0 + n) * H); // uniform
        float4 ea = er[0], eb4 = er[1];
        acc[0] += ea.x  * xv; acc[1] += ea.y  * xv;
        acc[2] += ea.z  * xv; acc[3] += ea.w  * xv;
        acc[4] += eb4.x * xv; acc[5] += eb4.y * xv;
        acc[6] += eb4.z * xv; acc[7] += eb4.w * xv;
    }
    float* pr = part + (size_t)(b * NCH + ch) * (H * C) + c;
    #pragma unroll
    for (int h = 0; h < H; ++h) pr[h * C] = acc[h];
}

// blocks 0..47: xw[b][j] = sum_ch part[b][ch][j]   (j = h*C+c, 3072 outputs)
// blocks 48..63: zp[b][s][h] = sum_{n in 512-row slice s} e[b][n][h]
__global__ __launch_bounds__(64) void k_reduce(const float* __restrict__ part,
                                               const float* __restrict__ e,
                                               float* __restrict__ xw,
                                               float* __restrict__ zp) {
    const int blk = blockIdx.x, tid = threadIdx.x;
    if (blk < 48) {
        const int i = blk * 64 + tid;              // 0..3071
        const int b = i / (H * C), j = i % (H * C);
        const float* pb = part + (size_t)b * NCH * H * C + j;
        float s = 0.f;
        for (int ch = 0; ch < NCH; ++ch) s += pb[(size_t)ch * H * C];
        xw[i] = s;
    } else {
        const int q = blk - 48;                    // 0..15
        const int b = q / 8, sl = q % 8;
        const float4* e4 = (const float4*)e + (size_t)b * (N * H / 4) + sl * 1024;
        float4 a = {0.f, 0.f, 0.f, 0.f};
        for (int k = 0; k < 16; ++k) {
            float4 v = e4[k * 64 + tid];           // lane parity fixes h-group
            a.x += v.x; a.y += v.y; a.z += v.z; a.w += v.w;
        }
        #pragma unroll
        for (int m = 2; m <= 32; m <<= 1) {
            a.x += __shfl_xor(a.x, m); a.y += __shfl_xor(a.y, m);
            a.z += __shfl_xor(a.z, m); a.w += __shfl_xor(a.w, m);
        }
        float4* zp4 = (float4*)zp;
        if (tid == 0) zp4[(b * 8 + sl) * 2 + 0] = a;   // h 0..3
        if (tid == 1) zp4[(b * 8 + sl) * 2 + 1] = a;   // h 4..7
    }
}

// obar[b][t] = (xw[b][h(t)] . Wv[t]) / Z[b][h],  4 outputs per 64-lane block
__global__ __launch_bounds__(64) void k_obar(const float* __restrict__ Wqkv,
                                             const float* __restrict__ xw,
                                             const float* __restrict__ zp,
                                             float* __restrict__ obar) {
    const int blk = blockIdx.x;                    // 0..95
    const int b = blk / 48, grp = blk % 48;
    const int l = threadIdx.x;
    const int t0 = grp * 4;
    const int h = t0 / D;                          // all 4 outputs share h (24 % 4 == 0)
    const float* xwh = xw + (size_t)b * H * C + h * C;
    float xv0 = xwh[l], xv1 = xwh[l + 64], xv2 = xwh[l + 128];
    float Z = 0.f;
    #pragma unroll
    for (int s = 0; s < 8; ++s) Z += zp[(b * 8 + s) * 8 + h];
    #pragma unroll
    for (int j = 0; j < 4; ++j) {
        const int t = t0 + j;
        const float* wv = Wqkv + (size_t)(2 * C + t) * C;
        float s = xv0 * wv[l] + xv1 * wv[l + 64] + xv2 * wv[l + 128];
        #pragma unroll
        for (int m = 1; m <= 32; m <<= 1) s += __shfl_xor(s, m);
        if (l == 0) obar[b * C + t] = s / Z;
    }
}

// y[b][o] = bproj[o] + obar[b] . Wproj[o]
__global__ __launch_bounds__(64) void k_y(const float* __restrict__ Wproj,
                                          const float* __restrict__ bproj,
                                          const float* __restrict__ obar,
                                          float* __restrict__ y) {
    const int blk = blockIdx.x;                    // 0..95
    const int b = blk / 48, grp = blk % 48;
    const int l = threadIdx.x;
    const float* ob = obar + (size_t)b * C;
    float ov0 = ob[l], ov1 = ob[l + 64], ov2 = ob[l + 128];
    #pragma unroll
    for (int j = 0; j < 4; ++j) {
        const int o = grp * 4 + j;
        const float* wp = Wproj + (size_t)o * C;
        float s = ov0 * wp[l] + ov1 * wp[l + 64] + ov2 * wp[l + 128];
        #pragma unroll
        for (int m = 1; m <= 32; m <<= 1) s += __shfl_xor(s, m);
        if (l == 0) y[b * C + o] = s + bproj[o];
    }
}

// out[b][n][:] = y[b][:]
__global__ __launch_bounds__(256) void k_bcast(const float* __restrict__ y,
                                               float* __restrict__ out) {
    const int perB4 = N * C / 4;                   // 196608
    int i = blockIdx.x * 1536 + threadIdx.x;
    float4* o4 = (float4*)out;
    #pragma unroll
    for (int k = 0; k < 6; ++k, i += 256) {
        int b  = i / perB4;
        int c4 = i % (C / 4);
        o4[i] = ((const float4*)(y + (size_t)b * C))[c4];
    }
}

extern "C" void kernel_launch(void* const* d_in, const int* in_sizes, int n_in,
                              void* d_out, int out_size, void* d_ws, size_t ws_size,
                              hipStream_t stream) {
    const float* x     = (const float*)d_in[0];
    const float* Wqkv  = (const float*)d_in[1];
    const float* Wproj = (const float*)d_in[2];
    const float* bproj = (const float*)d_in[3];
    const float* scale = (const float*)d_in[4];
    float* out = (float*)d_out;
    float* ws  = (float*)d_ws;
    float* wk   = ws + WK_OFF;
    float* e    = ws + E_OFF;
    float* part = ws + PART_OFF;
    float* xw   = ws + XW_OFF;
    float* zp   = ws + ZP_OFF;
    float* obar = ws + OBAR_OFF;
    float* y    = ws + Y_OFF;

    k_wk    <<<H,        192, 0, stream>>>(Wqkv, wk);
    k_e     <<<(B*N)/64, 64,  0, stream>>>(x, wk, scale, e);
    k_part  <<<B*NCH,    192, 0, stream>>>(x, e, part);
    k_reduce<<<64,       64,  0, stream>>>(part, e, xw, zp);
    k_obar  <<<2*48,     64,  0, stream>>>(Wqkv, xw, zp, obar);
    k_y     <<<2*48,     64,  0, stream>>>(Wproj, bproj, obar, y);
    k_bcast <<<256,      256, 0, stream>>>(y, out);
}

// Round 3
// 86.662 us; speedup vs baseline: 1.2640x; 1.1221x over previous
//
#include <hip/hip_runtime.h>

#define B 2
#define N 4096
#define C 192
#define H 8
#define D 24
#define ROWS 32                 // rows per chunk
#define NCHUNK (B * N / ROWS)   // 256 chunks total
#define PJ 1544                 // per-chunk partial floats: 1536 xw + 8 z

// ws layout (float offsets)
#define PART_OFF 0              // part [NCHUNK][PJ]  = 395264
#define XW_OFF   395264         // xw   [B][PJ]       = 3088

// A: one block per 32-row chunk.
//   wk[h][c] = sum_d Wqkv[(C+h*D+d)*C + c]           (in LDS, padded stride 196)
//   e[r][h]  = exp(scale * dot(x_row, wk[h]))        (in LDS only)
//   part[chunk][h*C+c]   = sum_r e[r][h] * x[r][c]
//   part[chunk][1536+h]  = sum_r e[r][h]
__global__ __launch_bounds__(256) void kA(const float* __restrict__ x,
                                          const float* __restrict__ Wqkv,
                                          const float* __restrict__ scale,
                                          float* __restrict__ part) {
    __shared__ __align__(16) float wk[H * 196];
    __shared__ __align__(16) float lx[ROWS * 196];
    __shared__ float le[ROWS * 9];
    const int tid = threadIdx.x;
    const int blk = blockIdx.x;                 // chunk id

    // wk (each block builds its own copy; Wqkv slice is L2-hot)
    for (int i = tid; i < H * C; i += 256) {
        const int h = i / C, c = i - h * C;
        const float* wr = Wqkv + (size_t)(C + h * D) * C + c;
        float s = 0.f;
        #pragma unroll
        for (int d = 0; d < D; ++d) s += wr[d * C];
        wk[h * 196 + c] = s;
    }
    // stage 32 rows of x (coalesced float4), padded LDS rows
    const float4* xb = (const float4*)(x + (size_t)blk * ROWS * C);
    #pragma unroll
    for (int k = 0; k < 6; ++k) {
        const int f4 = tid + k * 256;           // 0..1535
        const int r = f4 / 48, c4 = f4 - r * 48;
        *(float4*)&lx[r * 196 + c4 * 4] = xb[f4];
    }
    __syncthreads();

    // e: thread -> (r = tid>>3, h = tid&7)
    {
        const int r = tid >> 3, h = tid & 7;
        const float4* xr = (const float4*)&lx[r * 196];
        const float4* wh = (const float4*)&wk[h * 196];
        float acc = 0.f;
        #pragma unroll 8
        for (int c4 = 0; c4 < 48; ++c4) {
            float4 a = xr[c4], w = wh[c4];
            acc += a.x * w.x + a.y * w.y + a.z * w.z + a.w * w.w;
        }
        le[r * 9 + h] = __expf(acc * scale[0]);
    }
    __syncthreads();

    // partials: thread -> (h = tid>>5, c = (tid&31) + 32j)
    const int h = tid >> 5, c0 = tid & 31;
    float acc[6] = {};
    float zacc = 0.f;
    for (int r = 0; r < ROWS; ++r) {
        const float e = le[r * 9 + h];
        if (c0 == 0) zacc += e;
        #pragma unroll
        for (int j = 0; j < 6; ++j) acc[j] += e * lx[r * 196 + c0 + 32 * j];
    }
    float* pb = part + (size_t)blk * PJ;
    #pragma unroll
    for (int j = 0; j < 6; ++j) pb[h * C + c0 + 32 * j] = acc[j];
    if (c0 == 0) pb[1536 + h] = zacc;
}

// B: xw[b][j] = sum_{ch<128} part[b*128+ch][j]   (3088 outputs incl. z)
__global__ __launch_bounds__(256) void kB(const float* __restrict__ part,
                                          float* __restrict__ xw) {
    const int i = blockIdx.x * 256 + threadIdx.x;
    if (i >= B * PJ) return;
    const int b = i / PJ, j = i - b * PJ;
    const float* p = part + (size_t)(b * 128) * PJ + j;
    float s0 = 0.f, s1 = 0.f, s2 = 0.f, s3 = 0.f;
    for (int ch = 0; ch < 128; ch += 4) {
        s0 += p[(size_t)(ch + 0) * PJ];
        s1 += p[(size_t)(ch + 1) * PJ];
        s2 += p[(size_t)(ch + 2) * PJ];
        s3 += p[(size_t)(ch + 3) * PJ];
    }
    xw[i] = (s0 + s1) + (s2 + s3);
}

// C: per chunk-block: obar[t] = (xw[b][h*C:] . Wv[t]) / Z[h];
//    y[o] = bproj[o] + obar . Wproj[o];  out rows <- y
__global__ __launch_bounds__(256) void kC(const float* __restrict__ Wqkv,
                                          const float* __restrict__ Wproj,
                                          const float* __restrict__ bproj,
                                          const float* __restrict__ xw,
                                          float* __restrict__ out) {
    __shared__ __align__(16) float lxw[PJ];
    __shared__ __align__(16) float lobar[C];
    __shared__ __align__(16) float ly[C];
    const int tid = threadIdx.x;
    const int blk = blockIdx.x;                 // chunk id
    const int b = blk >> 7;

    for (int i = tid; i < PJ; i += 256) lxw[i] = xw[b * PJ + i];
    __syncthreads();

    if (tid < C) {
        const int h = tid / D;
        const float4* wv = (const float4*)(Wqkv + (size_t)(2 * C + tid) * C);
        const float4* xh = (const float4*)&lxw[h * C];
        float s = 0.f;
        #pragma unroll 8
        for (int c4 = 0; c4 < 48; ++c4) {
            float4 a = wv[c4], w = xh[c4];
            s += a.x * w.x + a.y * w.y + a.z * w.z + a.w * w.w;
        }
        lobar[tid] = s / lxw[1536 + h];
    }
    __syncthreads();

    if (tid < C) {
        const float4* wp = (const float4*)(Wproj + (size_t)tid * C);
        const float4* ob = (const float4*)lobar;
        float s = bproj[tid];
        #pragma unroll 8
        for (int c4 = 0; c4 < 48; ++c4) {
            float4 a = wp[c4], w = ob[c4];
            s += a.x * w.x + a.y * w.y + a.z * w.z + a.w * w.w;
        }
        ly[tid] = s;
    }
    __syncthreads();

    float4* o4 = (float4*)out + (size_t)blk * 1536;
    const float4* ly4 = (const float4*)ly;
    #pragma unroll
    for (int k = 0; k < 6; ++k) {
        const int f4 = tid + k * 256;
        o4[f4] = ly4[f4 % 48];
    }
}

extern "C" void kernel_launch(void* const* d_in, const int* in_sizes, int n_in,
                              void* d_out, int out_size, void* d_ws, size_t ws_size,
                              hipStream_t stream) {
    const float* x     = (const float*)d_in[0];
    const float* Wqkv  = (const float*)d_in[1];
    const float* Wproj = (const float*)d_in[2];
    const float* bproj = (const float*)d_in[3];
    const float* scale = (const float*)d_in[4];
    float* out  = (float*)d_out;
    float* ws   = (float*)d_ws;
    float* part = ws + PART_OFF;
    float* xw   = ws + XW_OFF;

    kA<<<NCHUNK, 256, 0, stream>>>(x, Wqkv, scale, part);
    kB<<<13,     256, 0, stream>>>(part, xw);
    kC<<<NCHUNK, 256, 0, stream>>>(Wqkv, Wproj, bproj, xw, out);
}